// Round 3
// baseline (1123.085 us; speedup 1.0000x reference)
//
#include <hip/hip_runtime.h>
#include <cstdint>
#include <cstddef>

#define B_SZ 8
#define T_LEN 4096
#define HD 1024
#define MTOT (B_SZ * T_LEN)   // 32768 tokens

typedef unsigned short u16;
typedef __attribute__((ext_vector_type(8))) short bf16x8;
typedef __attribute__((ext_vector_type(8))) unsigned short us8;
typedef __attribute__((ext_vector_type(4))) float f32x4;

static __device__ __forceinline__ float bf2f(u16 u) {
    union { unsigned i; float f; } v; v.i = ((unsigned)u) << 16; return v.f;
}
static __device__ __forceinline__ u16 f2bf(float f) {
    union { float f; unsigned i; } v; v.f = f;
    unsigned r = v.i + 0x7fffu + ((v.i >> 16) & 1u);
    return (u16)(r >> 16);
}
static __device__ __forceinline__ float sigm(float x) { return 1.f / (1.f + __expf(-x)); }
static __device__ __forceinline__ float tanh_fast(float x) { return 1.f - 2.f / (1.f + __expf(2.f * x)); }

static __device__ __forceinline__ void gload_lds16(const void* g, void* l) {
    __builtin_amdgcn_global_load_lds((const __attribute__((address_space(1))) void*)g,
                                     (__attribute__((address_space(3))) void*)l, 16, 0, 0);
}

// ---- K0: weights f32 -> bf16: wcat = [v(1024); g(1024); t(1024); r(1024)], wob = Wo
__global__ __launch_bounds__(256) void prep_weights(
    const float* __restrict__ Wp, const float* __restrict__ Wg,
    const float* __restrict__ Wt, const float* __restrict__ Wr,
    const float* __restrict__ Wo, u16* __restrict__ wcat, u16* __restrict__ wob)
{
    int i = blockIdx.x * 256 + threadIdx.x;   // float4 index
    const int T1 = 4096 * 256;
    const int T2 = 1024 * 256;
    if (i < T1) {
        int r = i >> 8, kq = i & 255;
        float4 v;
        if      (r < 1024)  v = ((const float4*)Wp)[(size_t)(r + 1) * 256 + kq];   // v-rows: Wp[1..1024]
        else if (r < 2048)  v = ((const float4*)Wg)[(size_t)(r - 1024) * 256 + kq];
        else if (r < 3072)  v = ((const float4*)Wt)[(size_t)(r - 2048) * 256 + kq];
        else                v = ((const float4*)Wr)[(size_t)(r - 3072) * 256 + kq];
        ushort4 o; o.x = f2bf(v.x); o.y = f2bf(v.y); o.z = f2bf(v.z); o.w = f2bf(v.w);
        ((ushort4*)wcat)[i] = o;
    } else if (i < T1 + T2) {
        int j = i - T1;
        float4 v = ((const float4*)Wo)[j];
        ushort4 o; o.x = f2bf(v.x); o.y = f2bf(v.y); o.z = f2bf(v.z); o.w = f2bf(v.w);
        ((ushort4*)wob)[j] = o;
    }
}

// ---- K1: LayerNorm (f32) -> xn bf16, fused u[m] = xn_f32 . Wp[0] + bp[0] ----
__global__ __launch_bounds__(256) void ln_kernel(
    const float* __restrict__ x, const float* __restrict__ gamma,
    const float* __restrict__ beta, const float* __restrict__ Wp,
    const float* __restrict__ bp, u16* __restrict__ xnb, float* __restrict__ u)
{
    __shared__ float red[8];
    const int row = blockIdx.x, tid = threadIdx.x;
    const float4 v = ((const float4*)(x + (size_t)row * HD))[tid];
    float s  = v.x + v.y + v.z + v.w;
    float sq = v.x * v.x + v.y * v.y + v.z * v.z + v.w * v.w;
    #pragma unroll
    for (int off = 32; off > 0; off >>= 1) {
        s  += __shfl_down(s, off);
        sq += __shfl_down(sq, off);
    }
    if ((tid & 63) == 0) { red[tid >> 6] = s; red[4 + (tid >> 6)] = sq; }
    __syncthreads();
    const float S   = red[0] + red[1] + red[2] + red[3];
    const float SQ  = red[4] + red[5] + red[6] + red[7];
    const float mu  = S * (1.f / HD);
    const float var = SQ * (1.f / HD) - mu * mu;
    const float rs  = rsqrtf(var + 1e-5f);
    const float4 gg = ((const float4*)gamma)[tid];
    const float4 bb = ((const float4*)beta)[tid];
    const float x0 = (v.x - mu) * rs * gg.x + bb.x;
    const float x1 = (v.y - mu) * rs * gg.y + bb.y;
    const float x2 = (v.z - mu) * rs * gg.z + bb.z;
    const float x3 = (v.w - mu) * rs * gg.w + bb.w;
    ushort4 o; o.x = f2bf(x0); o.y = f2bf(x1); o.z = f2bf(x2); o.w = f2bf(x3);
    ((ushort4*)(xnb + (size_t)row * HD))[tid] = o;
    const float4 w0 = ((const float4*)Wp)[tid];
    float su = x0 * w0.x + x1 * w0.y + x2 * w0.z + x3 * w0.w;
    #pragma unroll
    for (int off = 32; off > 0; off >>= 1) su += __shfl_down(su, off);
    __syncthreads();
    if ((tid & 63) == 0) red[tid >> 6] = su;
    __syncthreads();
    if (tid == 0) u[row] = red[0] + red[1] + red[2] + red[3] + bp[0];
}

// ---- K2/K4: bf16 MFMA GEMM, 128x128 tile, BK=64, swizzled LDS, double-buffered
// 1D grid, XCD-chunked ntile-fast mapping. mode 0: epilogue -> transposed
// bf16 planes Vt/Gt/Tt/Rt [d][MTOT]; mode 1: plain f32 [m][1024] store.
__global__ __launch_bounds__(256) void gemm_bt(
    const u16* __restrict__ A, const u16* __restrict__ W, int mode, int ntsplit,
    const float* __restrict__ bp,
    u16* __restrict__ Vt, u16* __restrict__ Gt, u16* __restrict__ Tt, u16* __restrict__ Rt,
    float* __restrict__ Cout)
{
    __shared__ u16 sA[2][128 * 64];
    __shared__ u16 sB[2][128 * 64];
    // XCD-chunked bijective remap (gridDim.x % 8 == 0), ntile-fast for A-panel reuse
    const int nwg = gridDim.x;
    const int per = nwg >> 3;
    const int l = (blockIdx.x & 7) * per + (blockIdx.x >> 3);
    const int ntile = l % ntsplit;
    const int mtile = l / ntsplit;

    const int tid = threadIdx.x;
    const int lane = tid & 63, wave = tid >> 6;
    const u16* Ab = A + (size_t)mtile * 128 * 1024;
    const u16* Wb = W + (size_t)ntile * 128 * 1024;

    // staging map: linear LDS chunk q (16B) = row*8 + cl; stored chunk cl holds
    // global chunk cg = cl ^ (row&7)  (inverse-swizzled source, linear dest)
    int offj[4];
    #pragma unroll
    for (int j = 0; j < 4; ++j) {
        const int q = j * 256 + tid;
        const int row = q >> 3;
        const int cg = (q & 7) ^ (row & 7);
        offj[j] = row * 1024 + cg * 8;
    }

    #define GSTAGE(bf, k0) do {                                                  \
        _Pragma("unroll")                                                        \
        for (int j = 0; j < 4; ++j) {                                            \
            gload_lds16(Ab + offj[j] + (k0), &sA[bf][(j * 256 + tid) * 8]);      \
            gload_lds16(Wb + offj[j] + (k0), &sB[bf][(j * 256 + tid) * 8]);      \
        }                                                                        \
    } while (0)

    f32x4 acc[4][4] = {};
    const int wm = (wave >> 1) * 64, wn = (wave & 1) * 64;
    const int rA = lane & 15;
    const int clbase = lane & 7;

    GSTAGE(0, 0);
    __syncthreads();
    int cur = 0;
    for (int k0 = 0; k0 < 1024; k0 += 64) {
        if (k0 < 960) GSTAGE(cur ^ 1, k0 + 64);
        #pragma unroll
        for (int h = 0; h < 2; ++h) {
            const int cl = ((h << 2) + (lane >> 4)) ^ clbase;
            bf16x8 af[4], bfr[4];
            #pragma unroll
            for (int i = 0; i < 4; ++i)
                af[i]  = *(const bf16x8*)(&sA[cur][(wm + i * 16 + rA) * 64 + cl * 8]);
            #pragma unroll
            for (int i = 0; i < 4; ++i)
                bfr[i] = *(const bf16x8*)(&sB[cur][(wn + i * 16 + rA) * 64 + cl * 8]);
            #pragma unroll
            for (int mi = 0; mi < 4; ++mi)
                #pragma unroll
                for (int ni = 0; ni < 4; ++ni)
                    acc[mi][ni] = __builtin_amdgcn_mfma_f32_16x16x32_bf16(af[mi], bfr[ni], acc[mi][ni], 0, 0, 0);
        }
        __syncthreads();   // drains vmcnt(0): next buf staged; all reads of cur done
        cur ^= 1;
    }
    #undef GSTAGE

    const int seg = (ntile * 128) >> 10;          // block-uniform for mode 0
    #pragma unroll
    for (int mi = 0; mi < 4; ++mi) {
        #pragma unroll
        for (int ni = 0; ni < 4; ++ni) {
            const int n = ntile * 128 + wn + ni * 16 + (lane & 15);
            const int dd = n & 1023;
            #pragma unroll
            for (int j = 0; j < 4; ++j) {
                const int m = mtile * 128 + wm + mi * 16 + (lane >> 4) * 4 + j;
                float val = acc[mi][ni][j];
                if (mode == 1) {
                    Cout[(size_t)m * 1024 + n] = val;
                } else if (seg == 0) {
                    Vt[(size_t)dd * MTOT + m] = f2bf(val + bp[1 + dd]);
                } else if (seg == 1) {
                    Gt[(size_t)dd * MTOT + m] = f2bf(sigm(val));
                } else if (seg == 2) {
                    Tt[(size_t)dd * MTOT + m] = f2bf(tanh_fast(val));
                } else {
                    Rt[(size_t)dd * MTOT + m] = f2bf(sigm(val));
                }
            }
        }
    }
}

// ---- K3: LDS-free sequential dual cumsum over transposed planes -------------
// 128 blocks x 64 threads; lane owns one (b,d) chain; contiguous-in-t 16B loads
// with one-iteration register prefetch. f32 active + strict-sequential fp16 ghost.
__global__ __launch_bounds__(64) void scan_t(
    const u16* __restrict__ Vt, const u16* __restrict__ Gt,
    const u16* __restrict__ Tt, const u16* __restrict__ Rt,
    const float* __restrict__ ub, u16* __restrict__ outb,
    float* __restrict__ act_last, float* __restrict__ gho_last)
{
    const int lane = threadIdx.x;
    const int b  = blockIdx.x >> 4;
    const int d  = ((blockIdx.x & 15) << 6) + lane;
    const int bm0 = b * T_LEN;
    const size_t rbase = (size_t)d * MTOT + bm0;
    const us8* pv = (const us8*)(Vt + rbase);
    const us8* pg = (const us8*)(Gt + rbase);
    const us8* pt = (const us8*)(Tt + rbase);
    const us8* pr = (const us8*)(Rt + rbase);

    us8 cv[2], cg[2], ct_[2], cr[2];
    #pragma unroll
    for (int h = 0; h < 2; ++h) { cv[h] = pv[h]; cg[h] = pg[h]; ct_[h] = pt[h]; cr[h] = pr[h]; }

    float acc_a = 0.f;
    _Float16 acc_g = (_Float16)0.f;

    for (int c = 0; c < 256; ++c) {
        const int cn = (c < 255) ? c + 1 : c;
        us8 nv[2], ng[2], nt2[2], nr[2];
        #pragma unroll
        for (int h = 0; h < 2; ++h) {
            nv[h] = pv[cn * 2 + h]; ng[h] = pg[cn * 2 + h];
            nt2[h] = pt[cn * 2 + h]; nr[h] = pr[cn * 2 + h];
        }
        #pragma unroll
        for (int s = 0; s < 16; ++s) {
            const int h = s >> 3, e = s & 7;
            const int t = c * 16 + s;
            const float v  = bf2f(cv[h][e]);
            const float g  = bf2f(cg[h][e]);
            const float th = bf2f(ct_[h][e]);
            const float r  = bf2f(cr[h][e]);
            const float uu = ub[bm0 + t];                 // uniform -> s_load
            acc_a = fmaf(uu, v, acc_a);                   // f32 sequential cumsum
            acc_g = acc_g + (_Float16)(g * th);           // fp16 RNE sequential cumsum
            const float comb = acc_a + (float)acc_g;
            outb[(size_t)(bm0 + t) * HD + d] = f2bf(r * comb);
        }
        #pragma unroll
        for (int h = 0; h < 2; ++h) { cv[h] = nv[h]; cg[h] = ng[h]; ct_[h] = nt2[h]; cr[h] = nr[h]; }
    }
    act_last[(size_t)b * HD + d] = acc_a;
    gho_last[(size_t)b * HD + d] = (float)acc_g;
}

extern "C" void kernel_launch(void* const* d_in, const int* in_sizes, int n_in,
                              void* d_out, int out_size, void* d_ws, size_t ws_size,
                              hipStream_t stream)
{
    const float* x   = (const float*)d_in[0];
    const float* gam = (const float*)d_in[1];
    const float* bet = (const float*)d_in[2];
    const float* Wp  = (const float*)d_in[3];
    const float* bp  = (const float*)d_in[4];
    const float* Wg  = (const float*)d_in[5];
    const float* Wt  = (const float*)d_in[6];
    const float* Wr  = (const float*)d_in[7];
    const float* Wo  = (const float*)d_in[8];

    float* out0     = (float*)d_out;                       // (B,T,H) f32
    float* act_last = out0 + (size_t)MTOT * HD;            // (B,D) f32
    float* gho_last = act_last + (size_t)B_SZ * HD;        // (B,D) fp16-valued f32

    char* ws = (char*)d_ws;
    const size_t SZ = (size_t)MTOT * HD * 2;               // 64 MiB per bf16 plane
    u16* xnb  = (u16*)(ws);                                // xn bf16; later scan output
    u16* Vt   = (u16*)(ws + SZ);                           // transposed planes [d][MTOT]
    u16* Gt   = (u16*)(ws + 2 * SZ);
    u16* Tt   = (u16*)(ws + 3 * SZ);
    u16* Rt   = (u16*)(ws + 4 * SZ);
    u16* wcat = (u16*)(ws + 5 * SZ);                       // 8,388,608 B
    u16* wob  = (u16*)(ws + 5 * SZ + 8388608);             // 2,097,152 B
    float* ub = (float*)(ws + 5 * SZ + 8388608 + 2097152); // 131,072 B

    prep_weights<<<5120, 256, 0, stream>>>(Wp, Wg, Wt, Wr, Wo, wcat, wob);
    ln_kernel<<<MTOT, 256, 0, stream>>>(x, gam, bet, Wp, bp, xnb, ub);
    gemm_bt<<<8192, 256, 0, stream>>>(xnb, wcat, 0, 32, bp, Vt, Gt, Tt, Rt, nullptr);
    scan_t<<<128, 64, 0, stream>>>(Vt, Gt, Tt, Rt, ub, xnb /*out*/, act_last, gho_last);
    gemm_bt<<<2048, 256, 0, stream>>>(xnb, wob, 1, 8, bp, nullptr, nullptr, nullptr, nullptr, out0);
}

// Round 4
// 941.516 us; speedup vs baseline: 1.1928x; 1.1928x over previous
//
#include <hip/hip_runtime.h>
#include <cstdint>
#include <cstddef>

#define B_SZ 8
#define T_LEN 4096
#define HD 1024
#define MTOT (B_SZ * T_LEN)   // 32768 tokens

typedef unsigned short u16;
typedef __attribute__((ext_vector_type(8))) short bf16x8;
typedef __attribute__((ext_vector_type(8))) unsigned short us8;
typedef __attribute__((ext_vector_type(4))) float f32x4;

static __device__ __forceinline__ float bf2f(u16 u) {
    union { unsigned i; float f; } v; v.i = ((unsigned)u) << 16; return v.f;
}
static __device__ __forceinline__ u16 f2bf(float f) {
    union { float f; unsigned i; } v; v.f = f;
    unsigned r = v.i + 0x7fffu + ((v.i >> 16) & 1u);
    return (u16)(r >> 16);
}
static __device__ __forceinline__ float sigm(float x) { return 1.f / (1.f + __expf(-x)); }
static __device__ __forceinline__ float tanh_fast(float x) { return 1.f - 2.f / (1.f + __expf(2.f * x)); }

static __device__ __forceinline__ void gload_lds16(const void* g, void* l) {
    __builtin_amdgcn_global_load_lds((const __attribute__((address_space(1))) void*)g,
                                     (__attribute__((address_space(3))) void*)l, 16, 0, 0);
}

// ---- K0: weights f32 -> bf16: wcat = [v(1024); g(1024); t(1024); r(1024)], wob = Wo
__global__ __launch_bounds__(256) void prep_weights(
    const float* __restrict__ Wp, const float* __restrict__ Wg,
    const float* __restrict__ Wt, const float* __restrict__ Wr,
    const float* __restrict__ Wo, u16* __restrict__ wcat, u16* __restrict__ wob)
{
    int i = blockIdx.x * 256 + threadIdx.x;   // float4 index
    const int T1 = 4096 * 256;
    const int T2 = 1024 * 256;
    if (i < T1) {
        int r = i >> 8, kq = i & 255;
        float4 v;
        if      (r < 1024)  v = ((const float4*)Wp)[(size_t)(r + 1) * 256 + kq];   // v-rows: Wp[1..1024]
        else if (r < 2048)  v = ((const float4*)Wg)[(size_t)(r - 1024) * 256 + kq];
        else if (r < 3072)  v = ((const float4*)Wt)[(size_t)(r - 2048) * 256 + kq];
        else                v = ((const float4*)Wr)[(size_t)(r - 3072) * 256 + kq];
        ushort4 o; o.x = f2bf(v.x); o.y = f2bf(v.y); o.z = f2bf(v.z); o.w = f2bf(v.w);
        ((ushort4*)wcat)[i] = o;
    } else if (i < T1 + T2) {
        int j = i - T1;
        float4 v = ((const float4*)Wo)[j];
        ushort4 o; o.x = f2bf(v.x); o.y = f2bf(v.y); o.z = f2bf(v.z); o.w = f2bf(v.w);
        ((ushort4*)wob)[j] = o;
    }
}

// ---- K1: LayerNorm (f32) -> xn bf16, fused u[m] = xn_f32 . Wp[0] + bp[0] ----
__global__ __launch_bounds__(256) void ln_kernel(
    const float* __restrict__ x, const float* __restrict__ gamma,
    const float* __restrict__ beta, const float* __restrict__ Wp,
    const float* __restrict__ bp, u16* __restrict__ xnb, float* __restrict__ u)
{
    __shared__ float red[8];
    const int row = blockIdx.x, tid = threadIdx.x;
    const float4 v = ((const float4*)(x + (size_t)row * HD))[tid];
    float s  = v.x + v.y + v.z + v.w;
    float sq = v.x * v.x + v.y * v.y + v.z * v.z + v.w * v.w;
    #pragma unroll
    for (int off = 32; off > 0; off >>= 1) {
        s  += __shfl_down(s, off);
        sq += __shfl_down(sq, off);
    }
    if ((tid & 63) == 0) { red[tid >> 6] = s; red[4 + (tid >> 6)] = sq; }
    __syncthreads();
    const float S   = red[0] + red[1] + red[2] + red[3];
    const float SQ  = red[4] + red[5] + red[6] + red[7];
    const float mu  = S * (1.f / HD);
    const float var = SQ * (1.f / HD) - mu * mu;
    const float rs  = rsqrtf(var + 1e-5f);
    const float4 gg = ((const float4*)gamma)[tid];
    const float4 bb = ((const float4*)beta)[tid];
    const float x0 = (v.x - mu) * rs * gg.x + bb.x;
    const float x1 = (v.y - mu) * rs * gg.y + bb.y;
    const float x2 = (v.z - mu) * rs * gg.z + bb.z;
    const float x3 = (v.w - mu) * rs * gg.w + bb.w;
    ushort4 o; o.x = f2bf(x0); o.y = f2bf(x1); o.z = f2bf(x2); o.w = f2bf(x3);
    ((ushort4*)(xnb + (size_t)row * HD))[tid] = o;
    const float4 w0 = ((const float4*)Wp)[tid];
    float su = x0 * w0.x + x1 * w0.y + x2 * w0.z + x3 * w0.w;
    #pragma unroll
    for (int off = 32; off > 0; off >>= 1) su += __shfl_down(su, off);
    __syncthreads();
    if ((tid & 63) == 0) red[tid >> 6] = su;
    __syncthreads();
    if (tid == 0) u[row] = red[0] + red[1] + red[2] + red[3] + bp[0];
}

// ---- K2/K4: bf16 MFMA GEMM, 128x128 tile, BK=64, swizzled LDS (round-2 core)
// MODE 0: swapped-operand MFMA -> transposed tile; epilogue writes bf16 planes
//         Vt/Gt/Tt/Rt laid out [d][MTOT] with 16-lane-contiguous m (32B segs).
// MODE 1: normal orientation, plain f32 [m][1024] store.
template<int MODE>
__global__ __launch_bounds__(256) void gemm_bt(
    const u16* __restrict__ A, const u16* __restrict__ W,
    const float* __restrict__ bp,
    u16* __restrict__ Vt, u16* __restrict__ Gt, u16* __restrict__ Tt, u16* __restrict__ Rt,
    float* __restrict__ Cout)
{
    __shared__ u16 sA[128 * 64];
    __shared__ u16 sB[128 * 64];
    const int mtile = blockIdx.x, ntile = blockIdx.y;
    const int tid = threadIdx.x;
    const int lane = tid & 63, wave = tid >> 6;
    const u16* Ab = A + (size_t)mtile * 128 * 1024;
    const u16* Wb = W + (size_t)ntile * 128 * 1024;

    // staging map: linear LDS chunk q (16B) = row*8 + cl; stored chunk cl holds
    // global chunk cg = cl ^ (row&7)  (inverse-swizzled source, linear dest)
    int offj[4];
    #pragma unroll
    for (int j = 0; j < 4; ++j) {
        const int q = j * 256 + tid;
        const int row = q >> 3;
        const int cg = (q & 7) ^ (row & 7);
        offj[j] = row * 1024 + cg * 8;
    }

    f32x4 acc[4][4] = {};
    const int wm = (wave >> 1) * 64, wn = (wave & 1) * 64;
    const int rA = lane & 15;
    const int clbase = lane & 7;

    for (int k0 = 0; k0 < 1024; k0 += 64) {
        #pragma unroll
        for (int j = 0; j < 4; ++j) {
            gload_lds16(Ab + offj[j] + k0, sA + (size_t)(j * 256 + tid) * 8);
            gload_lds16(Wb + offj[j] + k0, sB + (size_t)(j * 256 + tid) * 8);
        }
        __syncthreads();
        #pragma unroll
        for (int h = 0; h < 2; ++h) {
            const int cl = ((h << 2) + (lane >> 4)) ^ clbase;
            bf16x8 af[4], bfr[4];
            #pragma unroll
            for (int i = 0; i < 4; ++i)
                af[i]  = *(const bf16x8*)(sA + (size_t)(wm + i * 16 + rA) * 64 + cl * 8);
            #pragma unroll
            for (int i = 0; i < 4; ++i)
                bfr[i] = *(const bf16x8*)(sB + (size_t)(wn + i * 16 + rA) * 64 + cl * 8);
            #pragma unroll
            for (int mi = 0; mi < 4; ++mi)
                #pragma unroll
                for (int ni = 0; ni < 4; ++ni) {
                    if (MODE == 0)   // swapped operands -> D[d][m] (transposed)
                        acc[mi][ni] = __builtin_amdgcn_mfma_f32_16x16x32_bf16(bfr[ni], af[mi], acc[mi][ni], 0, 0, 0);
                    else
                        acc[mi][ni] = __builtin_amdgcn_mfma_f32_16x16x32_bf16(af[mi], bfr[ni], acc[mi][ni], 0, 0, 0);
                }
        }
        __syncthreads();
    }

    if (MODE == 1) {
        #pragma unroll
        for (int mi = 0; mi < 4; ++mi) {
            #pragma unroll
            for (int ni = 0; ni < 4; ++ni) {
                const int n = ntile * 128 + wn + ni * 16 + (lane & 15);
                #pragma unroll
                for (int j = 0; j < 4; ++j) {
                    const int m = mtile * 128 + wm + mi * 16 + (lane >> 4) * 4 + j;
                    Cout[(size_t)m * 1024 + n] = acc[mi][ni][j];
                }
            }
        }
    } else {
        const int seg = ntile >> 3;               // 0:V 1:G 2:T 3:R (block-uniform)
        const int dbase = (ntile & 7) * 128 + wn; // plane-d base for this wave
        #pragma unroll
        for (int mi = 0; mi < 4; ++mi) {
            const int m = mtile * 128 + wm + mi * 16 + (lane & 15);
            #pragma unroll
            for (int ni = 0; ni < 4; ++ni) {
                #pragma unroll
                for (int j = 0; j < 4; ++j) {
                    const int d = dbase + ni * 16 + (lane >> 4) * 4 + j;
                    const float val = acc[mi][ni][j];
                    if (seg == 0) {
                        Vt[(size_t)d * MTOT + m] = f2bf(val + bp[1 + d]);
                    } else if (seg == 1) {
                        Gt[(size_t)d * MTOT + m] = f2bf(sigm(val));
                    } else if (seg == 2) {
                        Tt[(size_t)d * MTOT + m] = f2bf(tanh_fast(val));
                    } else {
                        Rt[(size_t)d * MTOT + m] = f2bf(sigm(val));
                    }
                }
            }
        }
    }
}

// ---- K3: LDS-free sequential dual cumsum over transposed planes -------------
// 128 blocks x 64 threads; lane owns one (b,d) chain; contiguous-in-t 16B loads
// with one-iteration register prefetch. f32 active + strict-sequential fp16 ghost.
__global__ __launch_bounds__(64) void scan_t(
    const u16* __restrict__ Vt, const u16* __restrict__ Gt,
    const u16* __restrict__ Tt, const u16* __restrict__ Rt,
    const float* __restrict__ ub, u16* __restrict__ outb,
    float* __restrict__ act_last, float* __restrict__ gho_last)
{
    const int lane = threadIdx.x;
    const int b  = blockIdx.x >> 4;
    const int d  = ((blockIdx.x & 15) << 6) + lane;
    const int bm0 = b * T_LEN;
    const size_t rbase = (size_t)d * MTOT + bm0;
    const us8* pv = (const us8*)(Vt + rbase);
    const us8* pg = (const us8*)(Gt + rbase);
    const us8* pt = (const us8*)(Tt + rbase);
    const us8* pr = (const us8*)(Rt + rbase);

    us8 cv[2], cg[2], ct_[2], cr[2];
    #pragma unroll
    for (int h = 0; h < 2; ++h) { cv[h] = pv[h]; cg[h] = pg[h]; ct_[h] = pt[h]; cr[h] = pr[h]; }

    float acc_a = 0.f;
    _Float16 acc_g = (_Float16)0.f;

    for (int c = 0; c < 256; ++c) {
        const int cn = (c < 255) ? c + 1 : c;
        us8 nv[2], ng[2], nt2[2], nr[2];
        #pragma unroll
        for (int h = 0; h < 2; ++h) {
            nv[h] = pv[cn * 2 + h]; ng[h] = pg[cn * 2 + h];
            nt2[h] = pt[cn * 2 + h]; nr[h] = pr[cn * 2 + h];
        }
        #pragma unroll
        for (int s = 0; s < 16; ++s) {
            const int h = s >> 3, e = s & 7;
            const int t = c * 16 + s;
            const float v  = bf2f(cv[h][e]);
            const float g  = bf2f(cg[h][e]);
            const float th = bf2f(ct_[h][e]);
            const float r  = bf2f(cr[h][e]);
            const float uu = ub[bm0 + t];                 // uniform -> s_load
            acc_a = fmaf(uu, v, acc_a);                   // f32 sequential cumsum
            acc_g = acc_g + (_Float16)(g * th);           // fp16 RNE sequential cumsum
            const float comb = acc_a + (float)acc_g;
            outb[(size_t)(bm0 + t) * HD + d] = f2bf(r * comb);
        }
        #pragma unroll
        for (int h = 0; h < 2; ++h) { cv[h] = nv[h]; cg[h] = ng[h]; ct_[h] = nt2[h]; cr[h] = nr[h]; }
    }
    act_last[(size_t)b * HD + d] = acc_a;
    gho_last[(size_t)b * HD + d] = (float)acc_g;
}

extern "C" void kernel_launch(void* const* d_in, const int* in_sizes, int n_in,
                              void* d_out, int out_size, void* d_ws, size_t ws_size,
                              hipStream_t stream)
{
    const float* x   = (const float*)d_in[0];
    const float* gam = (const float*)d_in[1];
    const float* bet = (const float*)d_in[2];
    const float* Wp  = (const float*)d_in[3];
    const float* bp  = (const float*)d_in[4];
    const float* Wg  = (const float*)d_in[5];
    const float* Wt  = (const float*)d_in[6];
    const float* Wr  = (const float*)d_in[7];
    const float* Wo  = (const float*)d_in[8];

    float* out0     = (float*)d_out;                       // (B,T,H) f32
    float* act_last = out0 + (size_t)MTOT * HD;            // (B,D) f32
    float* gho_last = act_last + (size_t)B_SZ * HD;        // (B,D) fp16-valued f32

    char* ws = (char*)d_ws;
    const size_t SZ = (size_t)MTOT * HD * 2;               // 64 MiB per bf16 plane
    u16* xnb  = (u16*)(ws);                                // xn bf16; later scan output
    u16* Vt   = (u16*)(ws + SZ);                           // transposed planes [d][MTOT]
    u16* Gt   = (u16*)(ws + 2 * SZ);
    u16* Tt   = (u16*)(ws + 3 * SZ);
    u16* Rt   = (u16*)(ws + 4 * SZ);
    u16* wcat = (u16*)(ws + 5 * SZ);                       // 8,388,608 B
    u16* wob  = (u16*)(ws + 5 * SZ + 8388608);             // 2,097,152 B
    float* ub = (float*)(ws + 5 * SZ + 8388608 + 2097152); // 131,072 B

    prep_weights<<<5120, 256, 0, stream>>>(Wp, Wg, Wt, Wr, Wo, wcat, wob);
    ln_kernel<<<MTOT, 256, 0, stream>>>(x, gam, bet, Wp, bp, xnb, ub);
    gemm_bt<0><<<dim3(256, 32), 256, 0, stream>>>(xnb, wcat, bp, Vt, Gt, Tt, Rt, nullptr);
    scan_t<<<128, 64, 0, stream>>>(Vt, Gt, Tt, Rt, ub, xnb /*out*/, act_last, gho_last);
    gemm_bt<1><<<dim3(256, 8), 256, 0, stream>>>(xnb, wob, bp, nullptr, nullptr, nullptr, nullptr, out0);
}